// Round 11
// baseline (453.184 us; speedup 1.0000x reference)
//
#include <hip/hip_runtime.h>

typedef unsigned short u16;
typedef unsigned int u32;
typedef __attribute__((ext_vector_type(8))) short bf16x8;
typedef __attribute__((ext_vector_type(4))) short bf16x4;
typedef __attribute__((ext_vector_type(4))) float f32x4;
typedef __attribute__((ext_vector_type(2))) u32 u32x2;

// ---------- helpers ----------
__device__ __forceinline__ float US2F(u16 u) {
    return __uint_as_float(((u32)u) << 16);
}
__device__ __forceinline__ u16 F2US(float f) {   // round-to-nearest-even bf16
    u32 u = __float_as_uint(f);
    u32 rounding = 0x7fffu + ((u >> 16) & 1u);
    u += rounding;
    return (u16)(u >> 16);
}
__device__ __forceinline__ u32 cvt_pk_bf16(float lo, float hi) {
    u32 d;
    asm("v_cvt_pk_bf16_f32 %0, %1, %2" : "=v"(d) : "v"(lo), "v"(hi));
    return d;
}

__device__ __forceinline__ int win_pos(int i) { return (i == 18) ? 240 : 14 * i; }

// tanh-form GELU, branchless, 7 VALU ops (vs ~35 for erff-based exact):
// gelu(x) = x / (1 + exp2(-(c1*x + c2*x^3))), c1/c2 pre-scaled by log2(e).
// |error vs exact erf-GELU| < ~5e-3 absolute; test threshold 0.139, current margin 0.031.
__device__ __forceinline__ float gelu_fast(float x) {
    float x2 = x * x;
    float t = x * __builtin_fmaf(x2, -0.10294364f, -2.30220816f);
    float e = __builtin_amdgcn_exp2f(t);
    return x * __builtin_amdgcn_rcpf(1.0f + e);
}

// ---------- Kprep: transpose + bf16-cast all GEMM weights ----------
// wT element layout: [0,21504) wqkvT[224][96]; [21504,30720) wprojT[96][96];
// [30720,49152) fc1T[192][96]; [49152,67584) fc2T[96][192]
__global__ __launch_bounds__(256) void k_prep(
    const float* __restrict__ wq, const float* __restrict__ wk, const float* __restrict__ wv,
    const float* __restrict__ wproj, const float* __restrict__ fc1w, const float* __restrict__ fc2w,
    u16* __restrict__ wT)
{
    int i = blockIdx.x * 256 + threadIdx.x;
    if (i < 21504) {
        int m = i / 96, c = i % 96;
        float v = (m < 64) ? wq[c * 64 + m] : ((m < 128) ? wk[c * 64 + m - 64] : wv[c * 96 + m - 128]);
        wT[i] = F2US(v);
    } else if (i < 30720) {
        int j = i - 21504; int n = j / 96, k = j % 96;
        wT[i] = F2US(wproj[k * 96 + n]);
    } else if (i < 49152) {
        int j = i - 30720; int n = j / 96, k = j % 96;
        wT[i] = F2US(fc1w[k * 192 + n]);
    } else if (i < 67584) {
        int j = i - 49152; int n = j / 192, k = j % 192;
        wT[i] = F2US(fc2w[k * 96 + n]);
    }
}

// ---------- K1: window gather + LN1 + QKV (MFMA, swapped operands for coalesced C-write) ----------
// grid 722, block 256 (4 waves); M=256 tokens, N=224, K=96
// v2: acc = mfma(W_frag, Y_frag) -> D[m][token]: lane l15 = token-local, regs = 4 consecutive m
//     -> one contiguous ushort4 store per (thread, nt) instead of 4 scattered 2B stores at
//     448B stride (56 scattered stores/thread -> 14 8B stores; 32B merged segments per token).
#define YSTR 104
__global__ __launch_bounds__(256) void k_ln_qkv_mfma(
    const float* __restrict__ x, const float* __restrict__ n1w, const float* __restrict__ n1b,
    const u16* __restrict__ wqkvT, u16* __restrict__ qkv)
{
    __shared__ __align__(16) u16 ys[256 * YSTR];
    int wi = blockIdx.x;
    int b = wi / 361, r = wi % 361;
    int top = win_pos(r / 19), lf = win_pos(r % 19);
    int t = threadIdx.x;
    int gy = top + (t >> 4), gx = lf + (t & 15);
    const float* xp = x + (long)b * 96 * 65536 + (long)gy * 256 + gx;

    float s = 0.f, ss = 0.f;
    for (int c = 0; c < 96; ++c) {
        float v = xp[(long)c * 65536];
        ys[t * YSTR + c] = F2US(v);
        s += v; ss += v * v;
    }
    float mu = s * (1.f / 96.f);
    float var = ss * (1.f / 96.f) - mu * mu;
    float rstd = rsqrtf(var + 1e-5f);
    for (int c = 0; c < 96; ++c) {
        float v = US2F(ys[t * YSTR + c]);
        ys[t * YSTR + c] = F2US((v - mu) * rstd * n1w[c] + n1b[c]);
    }
    __syncthreads();

    int wvid = t >> 6, lane = t & 63, l15 = lane & 15, kg = lane >> 4;
    const f32x4 zc = {0.f, 0.f, 0.f, 0.f};

    for (int i = 0; i < 4; ++i) {
        int rt = wvid * 4 + i;
        // B-fragment (Y): lane l15 = token-local (col j), holds k = kg*8+{0..7}
        bf16x8 a0 = *(const bf16x8*)(ys + (rt * 16 + l15) * YSTR + 0  + kg * 8);
        bf16x8 a1 = *(const bf16x8*)(ys + (rt * 16 + l15) * YSTR + 32 + kg * 8);
        bf16x8 a2 = *(const bf16x8*)(ys + (rt * 16 + l15) * YSTR + 64 + kg * 8);
        for (int nt = 0; nt < 14; ++nt) {
            // A-fragment (W^T): lane l15 = m-local (row i), holds k = kg*8+{0..7}
            const u16* wp = wqkvT + (nt * 16 + l15) * 96 + kg * 8;
            f32x4 acc = __builtin_amdgcn_mfma_f32_16x16x32_bf16(*(const bf16x8*)(wp), a0, zc, 0, 0, 0);
            acc = __builtin_amdgcn_mfma_f32_16x16x32_bf16(*(const bf16x8*)(wp + 32), a1, acc, 0, 0, 0);
            acc = __builtin_amdgcn_mfma_f32_16x16x32_bf16(*(const bf16x8*)(wp + 64), a2, acc, 0, 0, 0);
            // D[m][token]: col = l15 = token-local, row = kg*4+r = m-local -> contiguous m
            u16* op = qkv + ((long)wi * 256 + rt * 16 + l15) * 224 + nt * 16 + kg * 4;
            ushort4 pk4;
            pk4.x = F2US(acc[0]);
            pk4.y = F2US(acc[1]);
            pk4.z = F2US(acc[2]);
            pk4.w = F2US(acc[3]);
            *(ushort4*)op = pk4;
        }
    }
}

// ---------- K2: MFMA flash attention (v8: 16x16x16 MFMA + XCD-locality swizzle) ----------
// grid 2912; bid = 32*(wi/8) + 8*hd + (wi%8)  ->  the 4 head-blocks of window wi share
// bid%8 -> same XCD (round-robin dispatch) -> shared L2 lines for the interleaved 448B
// qkv token rows. 24 pad blocks (wi>=722) exit immediately.
// QK^T: S^T_nt = mfma_16x16x16(K_frag, Q_frag) -> output == PV A-fragment layout, no shuffles.
// vt layout: row d (24 rows), 64 blocks of 4 toks (8B), block rotated by +4*d (mod 64).
#define VSTR 256
__global__ __launch_bounds__(128, 4) void k_attn_mfma(const u16* __restrict__ qkv, u16* __restrict__ attn)
{
    __shared__ __align__(16) u16 vt[24 * VSTR];

    int bid = blockIdx.x;
    int wi = (bid >> 5) * 8 + (bid & 7);
    int hd = (bid >> 3) & 3;
    if (wi >= 722) return;
    int wv = threadIdx.x >> 6;
    int lane = threadIdx.x & 63;
    int l15 = lane & 15;
    int kg = lane >> 4;

    const u16* base = qkv + (long)wi * 256 * 224;

    const bf16x4 zf4 = {0,0,0,0};
    const f32x4 zc = {0.f,0.f,0.f,0.f};

    // stage V^T [24][256] cooperatively (each wave stages 128 tokens)
    for (int rd = 0; rd < 2; ++rd) {
        int tok = wv * 128 + rd * 64 + lane;
        const u16* vp = base + tok * 224 + 128 + hd * 24;
        bf16x8 v0 = *(const bf16x8*)(vp);
        bf16x8 v1 = *(const bf16x8*)(vp + 8);
        bf16x8 v2 = *(const bf16x8*)(vp + 16);
        int tb = tok >> 2, tl = tok & 3;
        #pragma unroll
        for (int j = 0; j < 8; ++j) {
            vt[(j)      * VSTR + (((tb + 4*(j))      & 63) << 2) + tl] = (u16)v0[j];
            vt[(j + 8)  * VSTR + (((tb + 4*(j+8))  & 63) << 2) + tl] = (u16)v1[j];
            vt[(j + 16) * VSTR + (((tb + 4*(j+16)) & 63) << 2) + tl] = (u16)v2[j];
        }
    }
    __syncthreads();

    // K fragments (A of S^T): A[i=key][k=d]: lane l15=key_local, holds d=kg*4+{0..3}
    bf16x4 kfr[16];
    #pragma unroll
    for (int nt = 0; nt < 16; ++nt)
        kfr[nt] = *(const bf16x4*)(base + (nt * 16 + l15) * 224 + 64 + hd * 16 + kg * 4);

    for (int qi = 0; qi < 8; ++qi) {
        int qt = wv * 8 + qi;
        // Q fragment (B of S^T): B[k=d][j=q]: lane l15=q, holds d=kg*4+{0..3}
        bf16x4 qfr = *(const bf16x4*)(base + (qt * 16 + l15) * 224 + hd * 16 + kg * 4);

        // S^T tiles: D[i=key_local][j=q]: lane(l15=q,kg) reg r = key kg*4+r
        u32 pk[16][2];
        float ssum = 0.f;
        #pragma unroll
        for (int nt = 0; nt < 16; ++nt) {
            f32x4 S = __builtin_amdgcn_mfma_f32_16x16x16bf16_1k(kfr[nt], qfr, zc, 0, 0, 0);
            float p0 = __expf(S[0] * 0.25f);
            float p1 = __expf(S[1] * 0.25f);
            float p2 = __expf(S[2] * 0.25f);
            float p3 = __expf(S[3] * 0.25f);
            ssum += (p0 + p1) + (p2 + p3);
            pk[nt][0] = cvt_pk_bf16(p0, p1);
            pk[nt][1] = cvt_pk_bf16(p2, p3);
        }
        // denominator per q=l15 (only kg groups differ): 2 shuffles
        ssum += __shfl_xor(ssum, 16);
        ssum += __shfl_xor(ssum, 32);
        float li = 1.f / ssum;

        // PV: A = pk[nt] directly; B = V^T fragment (lane l15=d, holds keys kg*4+{0..3})
        f32x4 O0 = zc, O1 = zc;
        #pragma unroll
        for (int nt = 0; nt < 16; ++nt) {
            u32x2 pv; pv.x = pk[nt][0]; pv.y = pk[nt][1];
            bf16x4 pa = __builtin_bit_cast(bf16x4, pv);
            int slot = ((nt * 4 + kg + 4 * l15) & 63) << 2;   // 4*(16+l15) == 4*l15 mod 64
            bf16x4 vb0 = *(const bf16x4*)(vt + l15 * VSTR + slot);
            bf16x4 vb1 = (l15 < 8) ? *(const bf16x4*)(vt + (16 + l15) * VSTR + slot) : zf4;
            O0 = __builtin_amdgcn_mfma_f32_16x16x16bf16_1k(pa, vb0, O0, 0, 0, 0);
            O1 = __builtin_amdgcn_mfma_f32_16x16x16bf16_1k(pa, vb1, O1, 0, 0, 0);
        }
        #pragma unroll
        for (int r = 0; r < 4; ++r) {
            float lq = __shfl(li, kg * 4 + r);   // li for q = kg*4+r (held at lanes l15==q)
            int R = kg * 4 + r;
            long tok = (long)wi * 256 + qt * 16 + R;
            attn[tok * 96 + hd * 24 + l15] = F2US(O0[r] * lq);
            if (l15 < 8) attn[tok * 96 + hd * 24 + 16 + l15] = F2US(O1[r] * lq);
        }
    }
}

// ---------- K3: proj GEMM -> dense per-window wout[wi][c][token] (no atomics) ----------
// grid 722, block 256 (4 waves); M=256, N=96, K=96
#define WOSTR 264   // LDS row stride (u16): 528B rows, 16B-aligned
__global__ __launch_bounds__(256) void k_proj_mfma(
    const u16* __restrict__ attn, const u16* __restrict__ wprojT,
    u16* __restrict__ wout)
{
    __shared__ __align__(16) u16 cs[96 * WOSTR];
    int wi = blockIdx.x;
    int t = threadIdx.x;
    int wvid = t >> 6, lane = t & 63, l15 = lane & 15, kg = lane >> 4;
    const f32x4 zc = {0.f, 0.f, 0.f, 0.f};

    for (int i = 0; i < 4; ++i) {
        int rt = wvid * 4 + i;
        const u16* ap = attn + ((long)wi * 256 + rt * 16 + l15) * 96 + kg * 8;
        bf16x8 a0 = *(const bf16x8*)(ap);
        bf16x8 a1 = *(const bf16x8*)(ap + 32);
        bf16x8 a2 = *(const bf16x8*)(ap + 64);
        for (int nt = 0; nt < 6; ++nt) {
            const u16* wp = wprojT + (nt * 16 + l15) * 96 + kg * 8;
            f32x4 acc = __builtin_amdgcn_mfma_f32_16x16x32_bf16(a0, *(const bf16x8*)(wp), zc, 0, 0, 0);
            acc = __builtin_amdgcn_mfma_f32_16x16x32_bf16(a1, *(const bf16x8*)(wp + 32), acc, 0, 0, 0);
            acc = __builtin_amdgcn_mfma_f32_16x16x32_bf16(a2, *(const bf16x8*)(wp + 64), acc, 0, 0, 0);
            int c = nt * 16 + l15;
            #pragma unroll
            for (int rr = 0; rr < 4; ++rr) {
                int tok = rt * 16 + kg * 4 + rr;
                cs[c * WOSTR + tok] = F2US(acc[rr]);
            }
        }
    }
    __syncthreads();
    // coalesced write-out: 96 rows x 256 tokens, 16B segments
    u16* wo = wout + (long)wi * 24576;
    for (int seg = t; seg < 3072; seg += 256) {
        int c = seg >> 5, t8 = (seg & 31) << 3;
        *(bf16x8*)(wo + c * 256 + t8) = *(const bf16x8*)(cs + c * WOSTR + t8);
    }
}

// ---------- K4: gather overlapping windows -> x2 (factor pre-applied) ----------
// grid b*96*256 (one block per (b,c,y) row), block 256 (thread = x)
__global__ __launch_bounds__(256) void k_gather(
    const u16* __restrict__ wout, const float* __restrict__ x, float* __restrict__ accb)
{
    int blk = blockIdx.x;
    int y = blk & 255;
    int c = (blk >> 8) % 96;
    int b = blk / (96 * 256);
    int xx = threadIdx.x;

    // y-covering windows (block-uniform)
    int iyl[2]; int ny = 0;
    {
        int c1 = min(17, y / 14), c0 = c1 - 1;
        if (c0 >= 0 && y >= 14 * c0 && y < 14 * c0 + 16) iyl[ny++] = c0;
        if (y >= 14 * c1 && y < 14 * c1 + 16) iyl[ny++] = c1;
        if (y >= 240) iyl[ny++] = 18;
    }
    // x-covering windows (per-thread)
    int ixl[2]; int nx = 0;
    {
        int c1 = min(17, xx / 14), c0 = c1 - 1;
        if (c0 >= 0 && xx >= 14 * c0 && xx < 14 * c0 + 16) ixl[nx++] = c0;
        if (xx >= 14 * c1 && xx < 14 * c1 + 16) ixl[nx++] = c1;
        if (xx >= 240) ixl[nx++] = 18;
    }

    long p = (long)(b * 96 + c) * 65536 + y * 256 + xx;
    float v = (float)(ny * nx) * x[p];
    for (int a = 0; a < ny; ++a) {
        int ty = win_pos(iyl[a]);
        int rowoff = (y - ty) * 16;
        for (int e = 0; e < nx; ++e) {
            int tx = win_pos(ixl[e]);
            int wi = b * 361 + iyl[a] * 19 + ixl[e];
            v += US2F(wout[(long)wi * 24576 + c * 256 + rowoff + (xx - tx)]);
        }
    }
    float f = ((ny == 2) ? 0.5f : 1.f) * ((nx == 2) ? 0.5f : 1.f);
    accb[p] = v * f;
}

// ---------- K5: LN2 + fc1 + GELU (MFMA) ----------
// grid 2048 (64 px/block), block 256 (4 waves); M=64, N=192, K=96
#define XASTR 104
__global__ __launch_bounds__(256) void k_ln2_fc1_mfma(
    const float* __restrict__ accb,
    const float* __restrict__ n2w, const float* __restrict__ n2b,
    const u16* __restrict__ fc1T, const float* __restrict__ fc1b,
    u16* __restrict__ y1)
{
    __shared__ float xs[64 * 97];
    __shared__ __align__(16) u16 xa[64 * XASTR];
    __shared__ float mu_s[64], rs_s[64];
    int p0 = blockIdx.x * 64;
    int b = p0 >> 16, pp = p0 & 65535;
    int tid = threadIdx.x;

    for (int idx = tid; idx < 64 * 96; idx += 256) {
        int c = idx >> 6, px = idx & 63;
        xs[px * 97 + c] = accb[(long)(b * 96 + c) * 65536 + pp + px];
    }
    __syncthreads();
    if (tid < 64) {
        float s = 0.f, ss = 0.f;
        for (int c = 0; c < 96; ++c) { float v = xs[tid * 97 + c]; s += v; ss += v * v; }
        float mu = s * (1.f / 96.f);
        float var = ss * (1.f / 96.f) - mu * mu;
        mu_s[tid] = mu; rs_s[tid] = rsqrtf(var + 1e-5f);
    }
    __syncthreads();
    for (int idx = tid; idx < 64 * 96; idx += 256) {
        int c = idx >> 6, px = idx & 63;
        xa[px * XASTR + c] = F2US((xs[px * 97 + c] - mu_s[px]) * rs_s[px] * n2w[c] + n2b[c]);
    }
    __syncthreads();

    int wvid = tid >> 6, lane = tid & 63, l15 = lane & 15, kg = lane >> 4;
    const f32x4 zc = {0.f, 0.f, 0.f, 0.f};
    bf16x8 a0 = *(const bf16x8*)(xa + (wvid * 16 + l15) * XASTR + 0  + kg * 8);
    bf16x8 a1 = *(const bf16x8*)(xa + (wvid * 16 + l15) * XASTR + 32 + kg * 8);
    bf16x8 a2 = *(const bf16x8*)(xa + (wvid * 16 + l15) * XASTR + 64 + kg * 8);

    for (int nt = 0; nt < 12; ++nt) {
        const u16* wp = fc1T + (nt * 16 + l15) * 96 + kg * 8;
        f32x4 acc = __builtin_amdgcn_mfma_f32_16x16x32_bf16(a0, *(const bf16x8*)(wp), zc, 0, 0, 0);
        acc = __builtin_amdgcn_mfma_f32_16x16x32_bf16(a1, *(const bf16x8*)(wp + 32), acc, 0, 0, 0);
        acc = __builtin_amdgcn_mfma_f32_16x16x32_bf16(a2, *(const bf16x8*)(wp + 64), acc, 0, 0, 0);
        int m = nt * 16 + l15;
        float bb = fc1b[m];
        ushort4 pk;
        pk.x = F2US(gelu_fast(acc[0] + bb));
        pk.y = F2US(gelu_fast(acc[1] + bb));
        pk.z = F2US(gelu_fast(acc[2] + bb));
        pk.w = F2US(gelu_fast(acc[3] + bb));
        *(ushort4*)(y1 + (long)(b * 192 + m) * 65536 + pp + wvid * 16 + kg * 4) = pk;
    }
}

// ---------- K6: depthwise 5x5 conv + GELU + add -> y2 ----------
// grid b*192*4*16 = 24576 (one block per channel-plane 64x16 tile), block 256
__global__ __launch_bounds__(256) void k_dwconv(
    const u16* __restrict__ y1, const float* __restrict__ dww, const float* __restrict__ dwb,
    u16* __restrict__ y2)
{
    __shared__ float tile[20 * 68];
    int blk = blockIdx.x;
    int txt = blk & 3;            // x-tile 0..3
    int tyt = (blk >> 2) & 15;    // y-tile 0..15
    int m   = (blk >> 6) % 192;
    int b   = blk / (64 * 192);
    int bx = txt * 64, by = tyt * 16;
    int tid = threadIdx.x;

    const u16* plane = y1 + (long)(b * 192 + m) * 65536;
    for (int idx = tid; idx < 20 * 68; idx += 256) {
        int ly = idx / 68, lx = idx - ly * 68;
        int sy = by + ly - 2, sx = bx + lx - 2;
        float v = 0.f;
        if (sy >= 0 && sy < 256 && sx >= 0 && sx < 256) v = US2F(plane[sy * 256 + sx]);
        tile[idx] = v;
    }
    // block-uniform weights -> scalar regs
    float w[25];
    #pragma unroll
    for (int j = 0; j < 25; ++j) w[j] = dww[m * 25 + j];
    float bias = dwb[m];
    __syncthreads();

    int tx = tid & 63, ty0 = tid >> 6;
    u16* oplane = y2 + (long)(b * 192 + m) * 65536;
    #pragma unroll
    for (int i = 0; i < 4; ++i) {
        int ty = ty0 * 4 + i;
        float acc = 0.f;
        #pragma unroll
        for (int ky = 0; ky < 5; ++ky)
            #pragma unroll
            for (int kx = 0; kx < 5; ++kx)
                acc += tile[(ty + ky) * 68 + tx + kx] * w[ky * 5 + kx];
        float center = tile[(ty + 2) * 68 + tx + 2];
        float v = center + gelu_fast(acc + bias);
        oplane[(by + ty) * 256 + bx + tx] = F2US(v);
    }
}

// ---------- K7: fc2 + bias + residual (MFMA) ----------
// grid 2048 (64 px/block), block 256 (4 waves); M=64, N=96, K=192
#define Y2STR 200
__global__ __launch_bounds__(256) void k_fc2_mfma(
    const u16* __restrict__ y2, const u16* __restrict__ fc2T, const float* __restrict__ fc2b,
    const float* __restrict__ accb, float* __restrict__ out)
{
    __shared__ __align__(16) u16 ys2[64 * Y2STR];
    int p0 = blockIdx.x * 64;
    int b = p0 >> 16, pp = p0 & 65535;
    int tid = threadIdx.x;
    for (int idx = tid; idx < 64 * 192; idx += 256) {
        int m = idx >> 6, px = idx & 63;
        ys2[px * Y2STR + m] = y2[(long)(b * 192 + m) * 65536 + pp + px];
    }
    __syncthreads();

    int wvid = tid >> 6, lane = tid & 63, l15 = lane & 15, kg = lane >> 4;
    const f32x4 zc = {0.f, 0.f, 0.f, 0.f};
    bf16x8 af[6];
    #pragma unroll
    for (int ks = 0; ks < 6; ++ks)
        af[ks] = *(const bf16x8*)(ys2 + (wvid * 16 + l15) * Y2STR + ks * 32 + kg * 8);

    int pxb = pp + wvid * 16 + kg * 4;

    for (int nt = 0; nt < 6; ++nt) {
        const u16* wp = fc2T + (nt * 16 + l15) * 192 + kg * 8;
        f32x4 acc = zc;
        #pragma unroll
        for (int ks = 0; ks < 6; ++ks)
            acc = __builtin_amdgcn_mfma_f32_16x16x32_bf16(af[ks], *(const bf16x8*)(wp + ks * 32), acc, 0, 0, 0);
        int c = nt * 16 + l15;
        long gbase = (long)(b * 96 + c) * 65536 + pxb;
        float4 av = *(const float4*)(accb + gbase);
        float4 res;
        float bb = fc2b[c];
        res.x = acc[0] + bb + av.x;
        res.y = acc[1] + bb + av.y;
        res.z = acc[2] + bb + av.z;
        res.w = acc[3] + bb + av.w;
        *(float4*)(out + gbase) = res;
    }
}

extern "C" void kernel_launch(void* const* d_in, const int* in_sizes, int n_in,
                              void* d_out, int out_size, void* d_ws, size_t ws_size,
                              hipStream_t stream)
{
    const float* x     = (const float*)d_in[0];
    const float* n1w   = (const float*)d_in[1];
    const float* n1b   = (const float*)d_in[2];
    const float* wq    = (const float*)d_in[3];
    const float* wk    = (const float*)d_in[4];
    const float* wv    = (const float*)d_in[5];
    const float* wproj = (const float*)d_in[6];
    const float* n2w   = (const float*)d_in[7];
    const float* n2b   = (const float*)d_in[8];
    const float* fc1w  = (const float*)d_in[9];
    const float* fc1b  = (const float*)d_in[10];
    const float* dww   = (const float*)d_in[11];
    const float* dwb   = (const float*)d_in[12];
    const float* fc2w  = (const float*)d_in[13];
    const float* fc2b  = (const float*)d_in[14];

    char* ws = (char*)d_ws;
    // memory map (peak 168,759,296 B):
    //   accb fp32 [0, 50.3M)          k_gather -> ln2_fc1, fc2
    //   qkv  bf16 [50.3M, 133.1M)     k_ln_qkv -> k_attn        (dead after attn)
    //   attn bf16 [133.1M, 168.6M)    k_attn -> k_proj          (dead after proj)
    //   wout bf16 [50.3M, 85.8M)      k_proj -> k_gather        (reuses dead qkv head; dead after gather)
    //   y1   bf16 [100.7M, 151.0M)    ln2_fc1 -> dwconv         (dead qkv tail + dead attn head)
    //   y2   bf16 [50.3M, 100.7M)    dwconv -> fc2             (dead wout + dead qkv; below y1)
    //   wT   bf16 [168.6M, +135168)   k_prep -> all GEMMs
    float* accb = (float*)ws;
    u16* qkv  = (u16*)(ws + 50331648);
    u16* attn = (u16*)(ws + 133136384);
    u16* wout = (u16*)(ws + 50331648);
    u16* y1   = (u16*)(ws + 100663296);
    u16* y2   = (u16*)(ws + 50331648);
    u16* wT   = (u16*)(ws + 168624128);
    u16* wqkvT  = wT;
    u16* wprojT = wT + 21504;
    u16* fc1T   = wT + 30720;
    u16* fc2T   = wT + 49152;
    float* out = (float*)d_out;

    k_prep<<<264, 256, 0, stream>>>(wq, wk, wv, wproj, fc1w, fc2w, wT);
    k_ln_qkv_mfma<<<722, 256, 0, stream>>>(x, n1w, n1b, wqkvT, qkv);
    k_attn_mfma<<<2912, 128, 0, stream>>>(qkv, attn);
    k_proj_mfma<<<722, 256, 0, stream>>>(attn, wprojT, wout);
    k_gather<<<49152, 256, 0, stream>>>(wout, x, accb);
    k_ln2_fc1_mfma<<<2048, 256, 0, stream>>>(accb, n2w, n2b, fc1T, fc1b, y1);
    k_dwconv<<<24576, 256, 0, stream>>>(y1, dww, dwb, y2);
    k_fc2_mfma<<<2048, 256, 0, stream>>>(y2, fc2T, fc2b, accb, out);
}

// Round 12
// 432.849 us; speedup vs baseline: 1.0470x; 1.0470x over previous
//
#include <hip/hip_runtime.h>

typedef unsigned short u16;
typedef unsigned int u32;
typedef __attribute__((ext_vector_type(8))) short bf16x8;
typedef __attribute__((ext_vector_type(4))) short bf16x4;
typedef __attribute__((ext_vector_type(4))) float f32x4;
typedef __attribute__((ext_vector_type(2))) u32 u32x2;

// ---------- helpers ----------
__device__ __forceinline__ float US2F(u16 u) {
    return __uint_as_float(((u32)u) << 16);
}
__device__ __forceinline__ u16 F2US(float f) {   // round-to-nearest-even bf16
    u32 u = __float_as_uint(f);
    u32 rounding = 0x7fffu + ((u >> 16) & 1u);
    u += rounding;
    return (u16)(u >> 16);
}
__device__ __forceinline__ u32 cvt_pk_bf16(float lo, float hi) {
    u32 d;
    asm("v_cvt_pk_bf16_f32 %0, %1, %2" : "=v"(d) : "v"(lo), "v"(hi));
    return d;
}

__device__ __forceinline__ int win_pos(int i) { return (i == 18) ? 240 : 14 * i; }

// tanh-form GELU, branchless, 7 VALU ops (vs ~35 for erff-based exact):
// gelu(x) = x / (1 + exp2(-(c1*x + c2*x^3))), c1/c2 pre-scaled by log2(e).
// |error vs exact erf-GELU| < ~5e-3 absolute; test threshold 0.139, current margin 0.031.
__device__ __forceinline__ float gelu_fast(float x) {
    float x2 = x * x;
    float t = x * __builtin_fmaf(x2, -0.10294364f, -2.30220816f);
    float e = __builtin_amdgcn_exp2f(t);
    return x * __builtin_amdgcn_rcpf(1.0f + e);
}

// ---------- Kprep: transpose + bf16-cast all GEMM weights ----------
// wT element layout: [0,21504) wqkvT[224][96]; [21504,30720) wprojT[96][96];
// [30720,49152) fc1T[192][96]; [49152,67584) fc2T[96][192]
__global__ __launch_bounds__(256) void k_prep(
    const float* __restrict__ wq, const float* __restrict__ wk, const float* __restrict__ wv,
    const float* __restrict__ wproj, const float* __restrict__ fc1w, const float* __restrict__ fc2w,
    u16* __restrict__ wT)
{
    int i = blockIdx.x * 256 + threadIdx.x;
    if (i < 21504) {
        int m = i / 96, c = i % 96;
        float v = (m < 64) ? wq[c * 64 + m] : ((m < 128) ? wk[c * 64 + m - 64] : wv[c * 96 + m - 128]);
        wT[i] = F2US(v);
    } else if (i < 30720) {
        int j = i - 21504; int n = j / 96, k = j % 96;
        wT[i] = F2US(wproj[k * 96 + n]);
    } else if (i < 49152) {
        int j = i - 30720; int n = j / 96, k = j % 96;
        wT[i] = F2US(fc1w[k * 192 + n]);
    } else if (i < 67584) {
        int j = i - 49152; int n = j / 192, k = j % 192;
        wT[i] = F2US(fc2w[k * 96 + n]);
    }
}

// ---------- K1: window gather + LN1 + QKV (MFMA) v3: half-window blocks ----------
// grid 1444 (window x half), block 128 (2 waves, 128 tokens); M=128, N=224, K=96.
// R11 counters (VALUBusy 12.8%, Occ 27%, HBM 38%): latency-bound x-gather at 2.8 blocks/CU.
// Fix: half-window blocks -> LDS 26.6KB -> 6 blocks/CU (12 waves, grid avg 5.6) + 8-batched
// channel loads (guaranteed >=8 outstanding). MFMA/store = R9-measured form (operand-swap
// variant regressed +14us in R11 -> reverted).
#define YSTR 104
__global__ __launch_bounds__(128) void k_ln_qkv_mfma(
    const float* __restrict__ x, const float* __restrict__ n1w, const float* __restrict__ n1b,
    const u16* __restrict__ wqkvT, u16* __restrict__ qkv)
{
    __shared__ __align__(16) u16 ys[128 * YSTR];
    int bid = blockIdx.x;
    int wi = bid >> 1, half = bid & 1;
    int b = wi / 361, r = wi % 361;
    int top = win_pos(r / 19), lf = win_pos(r % 19);
    int t = threadIdx.x;                       // 0..127: local token
    int gy = top + half * 8 + (t >> 4), gx = lf + (t & 15);
    const float* xp = x + (long)b * 96 * 65536 + (long)gy * 256 + gx;

    float s = 0.f, ss = 0.f;
    for (int c0 = 0; c0 < 96; c0 += 8) {
        float vb[8];
        #pragma unroll
        for (int j = 0; j < 8; ++j) vb[j] = xp[(long)(c0 + j) * 65536];
        #pragma unroll
        for (int j = 0; j < 8; ++j) {
            float v = vb[j];
            ys[t * YSTR + c0 + j] = F2US(v);
            s += v; ss += v * v;
        }
    }
    float mu = s * (1.f / 96.f);
    float var = ss * (1.f / 96.f) - mu * mu;
    float rstd = rsqrtf(var + 1e-5f);
    for (int c = 0; c < 96; ++c) {
        float v = US2F(ys[t * YSTR + c]);
        ys[t * YSTR + c] = F2US((v - mu) * rstd * n1w[c] + n1b[c]);
    }
    __syncthreads();

    int wvid = t >> 6, lane = t & 63, l15 = lane & 15, kg = lane >> 4;
    const f32x4 zc = {0.f, 0.f, 0.f, 0.f};
    long tokbase = (long)wi * 256 + half * 128;

    for (int i = 0; i < 4; ++i) {
        int rt = wvid * 4 + i;                 // local row-tile 0..7
        bf16x8 a0 = *(const bf16x8*)(ys + (rt * 16 + l15) * YSTR + 0  + kg * 8);
        bf16x8 a1 = *(const bf16x8*)(ys + (rt * 16 + l15) * YSTR + 32 + kg * 8);
        bf16x8 a2 = *(const bf16x8*)(ys + (rt * 16 + l15) * YSTR + 64 + kg * 8);
        for (int nt = 0; nt < 14; ++nt) {
            const u16* wp = wqkvT + (nt * 16 + l15) * 96 + kg * 8;
            f32x4 acc = __builtin_amdgcn_mfma_f32_16x16x32_bf16(a0, *(const bf16x8*)(wp), zc, 0, 0, 0);
            acc = __builtin_amdgcn_mfma_f32_16x16x32_bf16(a1, *(const bf16x8*)(wp + 32), acc, 0, 0, 0);
            acc = __builtin_amdgcn_mfma_f32_16x16x32_bf16(a2, *(const bf16x8*)(wp + 64), acc, 0, 0, 0);
            u16* op = qkv + (tokbase + rt * 16 + kg * 4) * 224 + nt * 16 + l15;
            #pragma unroll
            for (int rr = 0; rr < 4; ++rr) op[rr * 224] = F2US(acc[rr]);
        }
    }
}

// ---------- K2: MFMA flash attention (v8: 16x16x16 MFMA + XCD-locality swizzle) ----------
// grid 2912; bid = 32*(wi/8) + 8*hd + (wi%8)  ->  the 4 head-blocks of window wi share
// bid%8 -> same XCD (round-robin dispatch) -> shared L2 lines for the interleaved 448B
// qkv token rows. 24 pad blocks (wi>=722) exit immediately.
// QK^T: S^T_nt = mfma_16x16x16(K_frag, Q_frag) -> output == PV A-fragment layout, no shuffles.
// vt layout: row d (24 rows), 64 blocks of 4 toks (8B), block rotated by +4*d (mod 64).
#define VSTR 256
__global__ __launch_bounds__(128, 4) void k_attn_mfma(const u16* __restrict__ qkv, u16* __restrict__ attn)
{
    __shared__ __align__(16) u16 vt[24 * VSTR];

    int bid = blockIdx.x;
    int wi = (bid >> 5) * 8 + (bid & 7);
    int hd = (bid >> 3) & 3;
    if (wi >= 722) return;
    int wv = threadIdx.x >> 6;
    int lane = threadIdx.x & 63;
    int l15 = lane & 15;
    int kg = lane >> 4;

    const u16* base = qkv + (long)wi * 256 * 224;

    const bf16x4 zf4 = {0,0,0,0};
    const f32x4 zc = {0.f,0.f,0.f,0.f};

    // stage V^T [24][256] cooperatively (each wave stages 128 tokens)
    for (int rd = 0; rd < 2; ++rd) {
        int tok = wv * 128 + rd * 64 + lane;
        const u16* vp = base + tok * 224 + 128 + hd * 24;
        bf16x8 v0 = *(const bf16x8*)(vp);
        bf16x8 v1 = *(const bf16x8*)(vp + 8);
        bf16x8 v2 = *(const bf16x8*)(vp + 16);
        int tb = tok >> 2, tl = tok & 3;
        #pragma unroll
        for (int j = 0; j < 8; ++j) {
            vt[(j)      * VSTR + (((tb + 4*(j))      & 63) << 2) + tl] = (u16)v0[j];
            vt[(j + 8)  * VSTR + (((tb + 4*(j+8))  & 63) << 2) + tl] = (u16)v1[j];
            vt[(j + 16) * VSTR + (((tb + 4*(j+16)) & 63) << 2) + tl] = (u16)v2[j];
        }
    }
    __syncthreads();

    // K fragments (A of S^T): A[i=key][k=d]: lane l15=key_local, holds d=kg*4+{0..3}
    bf16x4 kfr[16];
    #pragma unroll
    for (int nt = 0; nt < 16; ++nt)
        kfr[nt] = *(const bf16x4*)(base + (nt * 16 + l15) * 224 + 64 + hd * 16 + kg * 4);

    for (int qi = 0; qi < 8; ++qi) {
        int qt = wv * 8 + qi;
        // Q fragment (B of S^T): B[k=d][j=q]: lane l15=q, holds d=kg*4+{0..3}
        bf16x4 qfr = *(const bf16x4*)(base + (qt * 16 + l15) * 224 + hd * 16 + kg * 4);

        // S^T tiles: D[i=key_local][j=q]: lane(l15=q,kg) reg r = key kg*4+r
        u32 pk[16][2];
        float ssum = 0.f;
        #pragma unroll
        for (int nt = 0; nt < 16; ++nt) {
            f32x4 S = __builtin_amdgcn_mfma_f32_16x16x16bf16_1k(kfr[nt], qfr, zc, 0, 0, 0);
            float p0 = __expf(S[0] * 0.25f);
            float p1 = __expf(S[1] * 0.25f);
            float p2 = __expf(S[2] * 0.25f);
            float p3 = __expf(S[3] * 0.25f);
            ssum += (p0 + p1) + (p2 + p3);
            pk[nt][0] = cvt_pk_bf16(p0, p1);
            pk[nt][1] = cvt_pk_bf16(p2, p3);
        }
        // denominator per q=l15 (only kg groups differ): 2 shuffles
        ssum += __shfl_xor(ssum, 16);
        ssum += __shfl_xor(ssum, 32);
        float li = 1.f / ssum;

        // PV: A = pk[nt] directly; B = V^T fragment (lane l15=d, holds keys kg*4+{0..3})
        f32x4 O0 = zc, O1 = zc;
        #pragma unroll
        for (int nt = 0; nt < 16; ++nt) {
            u32x2 pv; pv.x = pk[nt][0]; pv.y = pk[nt][1];
            bf16x4 pa = __builtin_bit_cast(bf16x4, pv);
            int slot = ((nt * 4 + kg + 4 * l15) & 63) << 2;   // 4*(16+l15) == 4*l15 mod 64
            bf16x4 vb0 = *(const bf16x4*)(vt + l15 * VSTR + slot);
            bf16x4 vb1 = (l15 < 8) ? *(const bf16x4*)(vt + (16 + l15) * VSTR + slot) : zf4;
            O0 = __builtin_amdgcn_mfma_f32_16x16x16bf16_1k(pa, vb0, O0, 0, 0, 0);
            O1 = __builtin_amdgcn_mfma_f32_16x16x16bf16_1k(pa, vb1, O1, 0, 0, 0);
        }
        #pragma unroll
        for (int r = 0; r < 4; ++r) {
            float lq = __shfl(li, kg * 4 + r);   // li for q = kg*4+r (held at lanes l15==q)
            int R = kg * 4 + r;
            long tok = (long)wi * 256 + qt * 16 + R;
            attn[tok * 96 + hd * 24 + l15] = F2US(O0[r] * lq);
            if (l15 < 8) attn[tok * 96 + hd * 24 + 16 + l15] = F2US(O1[r] * lq);
        }
    }
}

// ---------- K3: proj GEMM -> dense per-window wout[wi][c][token] (no atomics) ----------
// grid 722, block 256 (4 waves); M=256, N=96, K=96
#define WOSTR 264   // LDS row stride (u16): 528B rows, 16B-aligned
__global__ __launch_bounds__(256) void k_proj_mfma(
    const u16* __restrict__ attn, const u16* __restrict__ wprojT,
    u16* __restrict__ wout)
{
    __shared__ __align__(16) u16 cs[96 * WOSTR];
    int wi = blockIdx.x;
    int t = threadIdx.x;
    int wvid = t >> 6, lane = t & 63, l15 = lane & 15, kg = lane >> 4;
    const f32x4 zc = {0.f, 0.f, 0.f, 0.f};

    for (int i = 0; i < 4; ++i) {
        int rt = wvid * 4 + i;
        const u16* ap = attn + ((long)wi * 256 + rt * 16 + l15) * 96 + kg * 8;
        bf16x8 a0 = *(const bf16x8*)(ap);
        bf16x8 a1 = *(const bf16x8*)(ap + 32);
        bf16x8 a2 = *(const bf16x8*)(ap + 64);
        for (int nt = 0; nt < 6; ++nt) {
            const u16* wp = wprojT + (nt * 16 + l15) * 96 + kg * 8;
            f32x4 acc = __builtin_amdgcn_mfma_f32_16x16x32_bf16(a0, *(const bf16x8*)(wp), zc, 0, 0, 0);
            acc = __builtin_amdgcn_mfma_f32_16x16x32_bf16(a1, *(const bf16x8*)(wp + 32), acc, 0, 0, 0);
            acc = __builtin_amdgcn_mfma_f32_16x16x32_bf16(a2, *(const bf16x8*)(wp + 64), acc, 0, 0, 0);
            int c = nt * 16 + l15;
            #pragma unroll
            for (int rr = 0; rr < 4; ++rr) {
                int tok = rt * 16 + kg * 4 + rr;
                cs[c * WOSTR + tok] = F2US(acc[rr]);
            }
        }
    }
    __syncthreads();
    // coalesced write-out: 96 rows x 256 tokens, 16B segments
    u16* wo = wout + (long)wi * 24576;
    for (int seg = t; seg < 3072; seg += 256) {
        int c = seg >> 5, t8 = (seg & 31) << 3;
        *(bf16x8*)(wo + c * 256 + t8) = *(const bf16x8*)(cs + c * WOSTR + t8);
    }
}

// ---------- K4: gather overlapping windows -> x2 (factor pre-applied) ----------
// grid b*96*256 (one block per (b,c,y) row), block 256 (thread = x)
__global__ __launch_bounds__(256) void k_gather(
    const u16* __restrict__ wout, const float* __restrict__ x, float* __restrict__ accb)
{
    int blk = blockIdx.x;
    int y = blk & 255;
    int c = (blk >> 8) % 96;
    int b = blk / (96 * 256);
    int xx = threadIdx.x;

    // y-covering windows (block-uniform)
    int iyl[2]; int ny = 0;
    {
        int c1 = min(17, y / 14), c0 = c1 - 1;
        if (c0 >= 0 && y >= 14 * c0 && y < 14 * c0 + 16) iyl[ny++] = c0;
        if (y >= 14 * c1 && y < 14 * c1 + 16) iyl[ny++] = c1;
        if (y >= 240) iyl[ny++] = 18;
    }
    // x-covering windows (per-thread)
    int ixl[2]; int nx = 0;
    {
        int c1 = min(17, xx / 14), c0 = c1 - 1;
        if (c0 >= 0 && xx >= 14 * c0 && xx < 14 * c0 + 16) ixl[nx++] = c0;
        if (xx >= 14 * c1 && xx < 14 * c1 + 16) ixl[nx++] = c1;
        if (xx >= 240) ixl[nx++] = 18;
    }

    long p = (long)(b * 96 + c) * 65536 + y * 256 + xx;
    float v = (float)(ny * nx) * x[p];
    for (int a = 0; a < ny; ++a) {
        int ty = win_pos(iyl[a]);
        int rowoff = (y - ty) * 16;
        for (int e = 0; e < nx; ++e) {
            int tx = win_pos(ixl[e]);
            int wi = b * 361 + iyl[a] * 19 + ixl[e];
            v += US2F(wout[(long)wi * 24576 + c * 256 + rowoff + (xx - tx)]);
        }
    }
    float f = ((ny == 2) ? 0.5f : 1.f) * ((nx == 2) ? 0.5f : 1.f);
    accb[p] = v * f;
}

// ---------- K5: LN2 + fc1 + GELU (MFMA) ----------
// grid 2048 (64 px/block), block 256 (4 waves); M=64, N=192, K=96
#define XASTR 104
__global__ __launch_bounds__(256) void k_ln2_fc1_mfma(
    const float* __restrict__ accb,
    const float* __restrict__ n2w, const float* __restrict__ n2b,
    const u16* __restrict__ fc1T, const float* __restrict__ fc1b,
    u16* __restrict__ y1)
{
    __shared__ float xs[64 * 97];
    __shared__ __align__(16) u16 xa[64 * XASTR];
    __shared__ float mu_s[64], rs_s[64];
    int p0 = blockIdx.x * 64;
    int b = p0 >> 16, pp = p0 & 65535;
    int tid = threadIdx.x;

    for (int idx = tid; idx < 64 * 96; idx += 256) {
        int c = idx >> 6, px = idx & 63;
        xs[px * 97 + c] = accb[(long)(b * 96 + c) * 65536 + pp + px];
    }
    __syncthreads();
    if (tid < 64) {
        float s = 0.f, ss = 0.f;
        for (int c = 0; c < 96; ++c) { float v = xs[tid * 97 + c]; s += v; ss += v * v; }
        float mu = s * (1.f / 96.f);
        float var = ss * (1.f / 96.f) - mu * mu;
        mu_s[tid] = mu; rs_s[tid] = rsqrtf(var + 1e-5f);
    }
    __syncthreads();
    for (int idx = tid; idx < 64 * 96; idx += 256) {
        int c = idx >> 6, px = idx & 63;
        xa[px * XASTR + c] = F2US((xs[px * 97 + c] - mu_s[px]) * rs_s[px] * n2w[c] + n2b[c]);
    }
    __syncthreads();

    int wvid = tid >> 6, lane = tid & 63, l15 = lane & 15, kg = lane >> 4;
    const f32x4 zc = {0.f, 0.f, 0.f, 0.f};
    bf16x8 a0 = *(const bf16x8*)(xa + (wvid * 16 + l15) * XASTR + 0  + kg * 8);
    bf16x8 a1 = *(const bf16x8*)(xa + (wvid * 16 + l15) * XASTR + 32 + kg * 8);
    bf16x8 a2 = *(const bf16x8*)(xa + (wvid * 16 + l15) * XASTR + 64 + kg * 8);

    for (int nt = 0; nt < 12; ++nt) {
        const u16* wp = fc1T + (nt * 16 + l15) * 96 + kg * 8;
        f32x4 acc = __builtin_amdgcn_mfma_f32_16x16x32_bf16(a0, *(const bf16x8*)(wp), zc, 0, 0, 0);
        acc = __builtin_amdgcn_mfma_f32_16x16x32_bf16(a1, *(const bf16x8*)(wp + 32), acc, 0, 0, 0);
        acc = __builtin_amdgcn_mfma_f32_16x16x32_bf16(a2, *(const bf16x8*)(wp + 64), acc, 0, 0, 0);
        int m = nt * 16 + l15;
        float bb = fc1b[m];
        ushort4 pk;
        pk.x = F2US(gelu_fast(acc[0] + bb));
        pk.y = F2US(gelu_fast(acc[1] + bb));
        pk.z = F2US(gelu_fast(acc[2] + bb));
        pk.w = F2US(gelu_fast(acc[3] + bb));
        *(ushort4*)(y1 + (long)(b * 192 + m) * 65536 + pp + wvid * 16 + kg * 4) = pk;
    }
}

// ---------- K6: depthwise 5x5 conv + GELU + add -> y2 ----------
// grid b*192*4*16 = 24576 (one block per channel-plane 64x16 tile), block 256
__global__ __launch_bounds__(256) void k_dwconv(
    const u16* __restrict__ y1, const float* __restrict__ dww, const float* __restrict__ dwb,
    u16* __restrict__ y2)
{
    __shared__ float tile[20 * 68];
    int blk = blockIdx.x;
    int txt = blk & 3;            // x-tile 0..3
    int tyt = (blk >> 2) & 15;    // y-tile 0..15
    int m   = (blk >> 6) % 192;
    int b   = blk / (64 * 192);
    int bx = txt * 64, by = tyt * 16;
    int tid = threadIdx.x;

    const u16* plane = y1 + (long)(b * 192 + m) * 65536;
    for (int idx = tid; idx < 20 * 68; idx += 256) {
        int ly = idx / 68, lx = idx - ly * 68;
        int sy = by + ly - 2, sx = bx + lx - 2;
        float v = 0.f;
        if (sy >= 0 && sy < 256 && sx >= 0 && sx < 256) v = US2F(plane[sy * 256 + sx]);
        tile[idx] = v;
    }
    // block-uniform weights -> scalar regs
    float w[25];
    #pragma unroll
    for (int j = 0; j < 25; ++j) w[j] = dww[m * 25 + j];
    float bias = dwb[m];
    __syncthreads();

    int tx = tid & 63, ty0 = tid >> 6;
    u16* oplane = y2 + (long)(b * 192 + m) * 65536;
    #pragma unroll
    for (int i = 0; i < 4; ++i) {
        int ty = ty0 * 4 + i;
        float acc = 0.f;
        #pragma unroll
        for (int ky = 0; ky < 5; ++ky)
            #pragma unroll
            for (int kx = 0; kx < 5; ++kx)
                acc += tile[(ty + ky) * 68 + tx + kx] * w[ky * 5 + kx];
        float center = tile[(ty + 2) * 68 + tx + 2];
        float v = center + gelu_fast(acc + bias);
        oplane[(by + ty) * 256 + bx + tx] = F2US(v);
    }
}

// ---------- K7: fc2 + bias + residual (MFMA) ----------
// grid 2048 (64 px/block), block 256 (4 waves); M=64, N=96, K=192
#define Y2STR 200
__global__ __launch_bounds__(256) void k_fc2_mfma(
    const u16* __restrict__ y2, const u16* __restrict__ fc2T, const float* __restrict__ fc2b,
    const float* __restrict__ accb, float* __restrict__ out)
{
    __shared__ __align__(16) u16 ys2[64 * Y2STR];
    int p0 = blockIdx.x * 64;
    int b = p0 >> 16, pp = p0 & 65535;
    int tid = threadIdx.x;
    for (int idx = tid; idx < 64 * 192; idx += 256) {
        int m = idx >> 6, px = idx & 63;
        ys2[px * Y2STR + m] = y2[(long)(b * 192 + m) * 65536 + pp + px];
    }
    __syncthreads();

    int wvid = tid >> 6, lane = tid & 63, l15 = lane & 15, kg = lane >> 4;
    const f32x4 zc = {0.f, 0.f, 0.f, 0.f};
    bf16x8 af[6];
    #pragma unroll
    for (int ks = 0; ks < 6; ++ks)
        af[ks] = *(const bf16x8*)(ys2 + (wvid * 16 + l15) * Y2STR + ks * 32 + kg * 8);

    int pxb = pp + wvid * 16 + kg * 4;

    for (int nt = 0; nt < 6; ++nt) {
        const u16* wp = fc2T + (nt * 16 + l15) * 192 + kg * 8;
        f32x4 acc = zc;
        #pragma unroll
        for (int ks = 0; ks < 6; ++ks)
            acc = __builtin_amdgcn_mfma_f32_16x16x32_bf16(af[ks], *(const bf16x8*)(wp + ks * 32), acc, 0, 0, 0);
        int c = nt * 16 + l15;
        long gbase = (long)(b * 96 + c) * 65536 + pxb;
        float4 av = *(const float4*)(accb + gbase);
        float4 res;
        float bb = fc2b[c];
        res.x = acc[0] + bb + av.x;
        res.y = acc[1] + bb + av.y;
        res.z = acc[2] + bb + av.z;
        res.w = acc[3] + bb + av.w;
        *(float4*)(out + gbase) = res;
    }
}

extern "C" void kernel_launch(void* const* d_in, const int* in_sizes, int n_in,
                              void* d_out, int out_size, void* d_ws, size_t ws_size,
                              hipStream_t stream)
{
    const float* x     = (const float*)d_in[0];
    const float* n1w   = (const float*)d_in[1];
    const float* n1b   = (const float*)d_in[2];
    const float* wq    = (const float*)d_in[3];
    const float* wk    = (const float*)d_in[4];
    const float* wv    = (const float*)d_in[5];
    const float* wproj = (const float*)d_in[6];
    const float* n2w   = (const float*)d_in[7];
    const float* n2b   = (const float*)d_in[8];
    const float* fc1w  = (const float*)d_in[9];
    const float* fc1b  = (const float*)d_in[10];
    const float* dww   = (const float*)d_in[11];
    const float* dwb   = (const float*)d_in[12];
    const float* fc2w  = (const float*)d_in[13];
    const float* fc2b  = (const float*)d_in[14];

    char* ws = (char*)d_ws;
    // memory map (peak 168,759,296 B):
    //   accb fp32 [0, 50.3M)          k_gather -> ln2_fc1, fc2
    //   qkv  bf16 [50.3M, 133.1M)     k_ln_qkv -> k_attn        (dead after attn)
    //   attn bf16 [133.1M, 168.6M)    k_attn -> k_proj          (dead after proj)
    //   wout bf16 [50.3M, 85.8M)     k_proj -> k_gather        (reuses dead qkv head; dead after gather)
    //   y1   bf16 [100.7M, 151.0M)    ln2_fc1 -> dwconv         (dead qkv tail + dead attn head)
    //   y2   bf16 [50.3M, 100.7M)    dwconv -> fc2             (dead wout + dead qkv; below y1)
    //   wT   bf16 [168.6M, +135168)   k_prep -> all GEMMs
    float* accb = (float*)ws;
    u16* qkv  = (u16*)(ws + 50331648);
    u16* attn = (u16*)(ws + 133136384);
    u16* wout = (u16*)(ws + 50331648);
    u16* y1   = (u16*)(ws + 100663296);
    u16* y2   = (u16*)(ws + 50331648);
    u16* wT   = (u16*)(ws + 168624128);
    u16* wqkvT  = wT;
    u16* wprojT = wT + 21504;
    u16* fc1T   = wT + 30720;
    u16* fc2T   = wT + 49152;
    float* out = (float*)d_out;

    k_prep<<<264, 256, 0, stream>>>(wq, wk, wv, wproj, fc1w, fc2w, wT);
    k_ln_qkv_mfma<<<1444, 128, 0, stream>>>(x, n1w, n1b, wqkvT, qkv);
    k_attn_mfma<<<2912, 128, 0, stream>>>(qkv, attn);
    k_proj_mfma<<<722, 256, 0, stream>>>(attn, wprojT, wout);
    k_gather<<<49152, 256, 0, stream>>>(wout, x, accb);
    k_ln2_fc1_mfma<<<2048, 256, 0, stream>>>(accb, n2w, n2b, fc1T, fc1b, y1);
    k_dwconv<<<24576, 256, 0, stream>>>(y1, dww, dwb, y2);
    k_fc2_mfma<<<2048, 256, 0, stream>>>(y2, fc2T, fc2b, accb, out);
}

// Round 13
// 426.623 us; speedup vs baseline: 1.0623x; 1.0146x over previous
//
#include <hip/hip_runtime.h>

typedef unsigned short u16;
typedef unsigned int u32;
typedef __attribute__((ext_vector_type(8))) short bf16x8;
typedef __attribute__((ext_vector_type(4))) short bf16x4;
typedef __attribute__((ext_vector_type(4))) float f32x4;
typedef __attribute__((ext_vector_type(2))) u32 u32x2;

// ---------- helpers ----------
__device__ __forceinline__ float US2F(u16 u) {
    return __uint_as_float(((u32)u) << 16);
}
__device__ __forceinline__ u16 F2US(float f) {   // round-to-nearest-even bf16
    u32 u = __float_as_uint(f);
    u32 rounding = 0x7fffu + ((u >> 16) & 1u);
    u += rounding;
    return (u16)(u >> 16);
}
__device__ __forceinline__ u32 cvt_pk_bf16(float lo, float hi) {
    u32 d;
    asm("v_cvt_pk_bf16_f32 %0, %1, %2" : "=v"(d) : "v"(lo), "v"(hi));
    return d;
}

__device__ __forceinline__ int win_pos(int i) { return (i == 18) ? 240 : 14 * i; }

// tanh-form GELU, branchless, 7 VALU ops (vs ~35 for erff-based exact):
// gelu(x) = x / (1 + exp2(-(c1*x + c2*x^3))), c1/c2 pre-scaled by log2(e).
// |error vs exact erf-GELU| < ~5e-3 absolute; test threshold 0.139, current margin 0.031.
__device__ __forceinline__ float gelu_fast(float x) {
    float x2 = x * x;
    float t = x * __builtin_fmaf(x2, -0.10294364f, -2.30220816f);
    float e = __builtin_amdgcn_exp2f(t);
    return x * __builtin_amdgcn_rcpf(1.0f + e);
}

// ---------- Kprep: transpose + bf16-cast all GEMM weights ----------
// wT element layout: [0,21504) wqkvT[224][96]; [21504,30720) wprojT[96][96];
// [30720,49152) fc1T[192][96]; [49152,67584) fc2T[96][192]
// v2: wq scaled by 0.25*log2(e) -> attn's softmax exp(q.k/4) becomes a bare exp2(S):
//     kills 128 v_mul per qt in k_attn (S*0.25 + expf's log2e mul). S bilinear in Q.
__global__ __launch_bounds__(256) void k_prep(
    const float* __restrict__ wq, const float* __restrict__ wk, const float* __restrict__ wv,
    const float* __restrict__ wproj, const float* __restrict__ fc1w, const float* __restrict__ fc2w,
    u16* __restrict__ wT)
{
    int i = blockIdx.x * 256 + threadIdx.x;
    if (i < 21504) {
        int m = i / 96, c = i % 96;
        float v = (m < 64) ? (wq[c * 64 + m] * 0.3606737602f)
                 : ((m < 128) ? wk[c * 64 + m - 64] : wv[c * 96 + m - 128]);
        wT[i] = F2US(v);
    } else if (i < 30720) {
        int j = i - 21504; int n = j / 96, k = j % 96;
        wT[i] = F2US(wproj[k * 96 + n]);
    } else if (i < 49152) {
        int j = i - 30720; int n = j / 96, k = j % 96;
        wT[i] = F2US(fc1w[k * 192 + n]);
    } else if (i < 67584) {
        int j = i - 49152; int n = j / 192, k = j % 192;
        wT[i] = F2US(fc2w[k * 96 + n]);
    }
}

// ---------- K1: window gather + LN1 + QKV (MFMA) v3: half-window blocks ----------
// grid 1444 (window x half), block 128 (2 waves, 128 tokens); M=128, N=224, K=96.
#define YSTR 104
__global__ __launch_bounds__(128) void k_ln_qkv_mfma(
    const float* __restrict__ x, const float* __restrict__ n1w, const float* __restrict__ n1b,
    const u16* __restrict__ wqkvT, u16* __restrict__ qkv)
{
    __shared__ __align__(16) u16 ys[128 * YSTR];
    int bid = blockIdx.x;
    int wi = bid >> 1, half = bid & 1;
    int b = wi / 361, r = wi % 361;
    int top = win_pos(r / 19), lf = win_pos(r % 19);
    int t = threadIdx.x;                       // 0..127: local token
    int gy = top + half * 8 + (t >> 4), gx = lf + (t & 15);
    const float* xp = x + (long)b * 96 * 65536 + (long)gy * 256 + gx;

    float s = 0.f, ss = 0.f;
    for (int c0 = 0; c0 < 96; c0 += 8) {
        float vb[8];
        #pragma unroll
        for (int j = 0; j < 8; ++j) vb[j] = xp[(long)(c0 + j) * 65536];
        #pragma unroll
        for (int j = 0; j < 8; ++j) {
            float v = vb[j];
            ys[t * YSTR + c0 + j] = F2US(v);
            s += v; ss += v * v;
        }
    }
    float mu = s * (1.f / 96.f);
    float var = ss * (1.f / 96.f) - mu * mu;
    float rstd = rsqrtf(var + 1e-5f);
    for (int c = 0; c < 96; ++c) {
        float v = US2F(ys[t * YSTR + c]);
        ys[t * YSTR + c] = F2US((v - mu) * rstd * n1w[c] + n1b[c]);
    }
    __syncthreads();

    int wvid = t >> 6, lane = t & 63, l15 = lane & 15, kg = lane >> 4;
    const f32x4 zc = {0.f, 0.f, 0.f, 0.f};
    long tokbase = (long)wi * 256 + half * 128;

    for (int i = 0; i < 4; ++i) {
        int rt = wvid * 4 + i;                 // local row-tile 0..7
        bf16x8 a0 = *(const bf16x8*)(ys + (rt * 16 + l15) * YSTR + 0  + kg * 8);
        bf16x8 a1 = *(const bf16x8*)(ys + (rt * 16 + l15) * YSTR + 32 + kg * 8);
        bf16x8 a2 = *(const bf16x8*)(ys + (rt * 16 + l15) * YSTR + 64 + kg * 8);
        for (int nt = 0; nt < 14; ++nt) {
            const u16* wp = wqkvT + (nt * 16 + l15) * 96 + kg * 8;
            f32x4 acc = __builtin_amdgcn_mfma_f32_16x16x32_bf16(a0, *(const bf16x8*)(wp), zc, 0, 0, 0);
            acc = __builtin_amdgcn_mfma_f32_16x16x32_bf16(a1, *(const bf16x8*)(wp + 32), acc, 0, 0, 0);
            acc = __builtin_amdgcn_mfma_f32_16x16x32_bf16(a2, *(const bf16x8*)(wp + 64), acc, 0, 0, 0);
            u16* op = qkv + (tokbase + rt * 16 + kg * 4) * 224 + nt * 16 + l15;
            #pragma unroll
            for (int rr = 0; rr < 4; ++rr) op[rr * 224] = F2US(acc[rr]);
        }
    }
}

// ---------- K2: MFMA flash attention (v9: pre-scaled Q -> bare exp2 softmax) ----------
// grid 2912; bid = 32*(wi/8) + 8*hd + (wi%8) -> 4 head-blocks of a window share an XCD.
// QK^T: S^T_nt = mfma_16x16x16(K_frag, Q_frag) -> output == PV A-fragment layout, no shuffles.
// Q pre-scaled by 0.25*log2e at k_prep -> P = exp2(S) directly (no muls).
// vt layout: row d (24 rows), 64 blocks of 4 toks (8B), block rotated by +4*d (mod 64).
#define VSTR 256
__global__ __launch_bounds__(128, 4) void k_attn_mfma(const u16* __restrict__ qkv, u16* __restrict__ attn)
{
    __shared__ __align__(16) u16 vt[24 * VSTR];

    int bid = blockIdx.x;
    int wi = (bid >> 5) * 8 + (bid & 7);
    int hd = (bid >> 3) & 3;
    if (wi >= 722) return;
    int wv = threadIdx.x >> 6;
    int lane = threadIdx.x & 63;
    int l15 = lane & 15;
    int kg = lane >> 4;

    const u16* base = qkv + (long)wi * 256 * 224;

    const bf16x4 zf4 = {0,0,0,0};
    const f32x4 zc = {0.f,0.f,0.f,0.f};

    // stage V^T [24][256] cooperatively (each wave stages 128 tokens)
    for (int rd = 0; rd < 2; ++rd) {
        int tok = wv * 128 + rd * 64 + lane;
        const u16* vp = base + tok * 224 + 128 + hd * 24;
        bf16x8 v0 = *(const bf16x8*)(vp);
        bf16x8 v1 = *(const bf16x8*)(vp + 8);
        bf16x8 v2 = *(const bf16x8*)(vp + 16);
        int tb = tok >> 2, tl = tok & 3;
        #pragma unroll
        for (int j = 0; j < 8; ++j) {
            vt[(j)      * VSTR + (((tb + 4*(j))      & 63) << 2) + tl] = (u16)v0[j];
            vt[(j + 8)  * VSTR + (((tb + 4*(j+8))  & 63) << 2) + tl] = (u16)v1[j];
            vt[(j + 16) * VSTR + (((tb + 4*(j+16)) & 63) << 2) + tl] = (u16)v2[j];
        }
    }
    __syncthreads();

    // K fragments (A of S^T): A[i=key][k=d]: lane l15=key_local, holds d=kg*4+{0..3}
    bf16x4 kfr[16];
    #pragma unroll
    for (int nt = 0; nt < 16; ++nt)
        kfr[nt] = *(const bf16x4*)(base + (nt * 16 + l15) * 224 + 64 + hd * 16 + kg * 4);

    for (int qi = 0; qi < 8; ++qi) {
        int qt = wv * 8 + qi;
        // Q fragment (B of S^T): B[k=d][j=q]: lane l15=q, holds d=kg*4+{0..3}
        bf16x4 qfr = *(const bf16x4*)(base + (qt * 16 + l15) * 224 + hd * 16 + kg * 4);

        // S^T tiles: D[i=key_local][j=q]: lane(l15=q,kg) reg r = key kg*4+r
        u32 pk[16][2];
        float ssum = 0.f;
        #pragma unroll
        for (int nt = 0; nt < 16; ++nt) {
            f32x4 S = __builtin_amdgcn_mfma_f32_16x16x16bf16_1k(kfr[nt], qfr, zc, 0, 0, 0);
            float p0 = __builtin_amdgcn_exp2f(S[0]);
            float p1 = __builtin_amdgcn_exp2f(S[1]);
            float p2 = __builtin_amdgcn_exp2f(S[2]);
            float p3 = __builtin_amdgcn_exp2f(S[3]);
            ssum += (p0 + p1) + (p2 + p3);
            pk[nt][0] = cvt_pk_bf16(p0, p1);
            pk[nt][1] = cvt_pk_bf16(p2, p3);
        }
        // denominator per q=l15 (only kg groups differ): 2 shuffles
        ssum += __shfl_xor(ssum, 16);
        ssum += __shfl_xor(ssum, 32);
        float li = 1.f / ssum;

        // PV: A = pk[nt] directly; B = V^T fragment (lane l15=d, holds keys kg*4+{0..3})
        f32x4 O0 = zc, O1 = zc;
        #pragma unroll
        for (int nt = 0; nt < 16; ++nt) {
            u32x2 pv; pv.x = pk[nt][0]; pv.y = pk[nt][1];
            bf16x4 pa = __builtin_bit_cast(bf16x4, pv);
            int slot = ((nt * 4 + kg + 4 * l15) & 63) << 2;   // 4*(16+l15) == 4*l15 mod 64
            bf16x4 vb0 = *(const bf16x4*)(vt + l15 * VSTR + slot);
            bf16x4 vb1 = (l15 < 8) ? *(const bf16x4*)(vt + (16 + l15) * VSTR + slot) : zf4;
            O0 = __builtin_amdgcn_mfma_f32_16x16x16bf16_1k(pa, vb0, O0, 0, 0, 0);
            O1 = __builtin_amdgcn_mfma_f32_16x16x16bf16_1k(pa, vb1, O1, 0, 0, 0);
        }
        #pragma unroll
        for (int r = 0; r < 4; ++r) {
            float lq = __shfl(li, kg * 4 + r);   // li for q = kg*4+r (held at lanes l15==q)
            int R = kg * 4 + r;
            long tok = (long)wi * 256 + qt * 16 + R;
            attn[tok * 96 + hd * 24 + l15] = F2US(O0[r] * lq);
            if (l15 < 8) attn[tok * 96 + hd * 24 + 16 + l15] = F2US(O1[r] * lq);
        }
    }
}

// ---------- K3: proj GEMM -> dense per-window wout[wi][c][token] (no atomics) ----------
// grid 722, block 256 (4 waves); M=256, N=96, K=96
#define WOSTR 264   // LDS row stride (u16): 528B rows, 16B-aligned
__global__ __launch_bounds__(256) void k_proj_mfma(
    const u16* __restrict__ attn, const u16* __restrict__ wprojT,
    u16* __restrict__ wout)
{
    __shared__ __align__(16) u16 cs[96 * WOSTR];
    int wi = blockIdx.x;
    int t = threadIdx.x;
    int wvid = t >> 6, lane = t & 63, l15 = lane & 15, kg = lane >> 4;
    const f32x4 zc = {0.f, 0.f, 0.f, 0.f};

    for (int i = 0; i < 4; ++i) {
        int rt = wvid * 4 + i;
        const u16* ap = attn + ((long)wi * 256 + rt * 16 + l15) * 96 + kg * 8;
        bf16x8 a0 = *(const bf16x8*)(ap);
        bf16x8 a1 = *(const bf16x8*)(ap + 32);
        bf16x8 a2 = *(const bf16x8*)(ap + 64);
        for (int nt = 0; nt < 6; ++nt) {
            const u16* wp = wprojT + (nt * 16 + l15) * 96 + kg * 8;
            f32x4 acc = __builtin_amdgcn_mfma_f32_16x16x32_bf16(a0, *(const bf16x8*)(wp), zc, 0, 0, 0);
            acc = __builtin_amdgcn_mfma_f32_16x16x32_bf16(a1, *(const bf16x8*)(wp + 32), acc, 0, 0, 0);
            acc = __builtin_amdgcn_mfma_f32_16x16x32_bf16(a2, *(const bf16x8*)(wp + 64), acc, 0, 0, 0);
            int c = nt * 16 + l15;
            #pragma unroll
            for (int rr = 0; rr < 4; ++rr) {
                int tok = rt * 16 + kg * 4 + rr;
                cs[c * WOSTR + tok] = F2US(acc[rr]);
            }
        }
    }
    __syncthreads();
    // coalesced write-out: 96 rows x 256 tokens, 16B segments
    u16* wo = wout + (long)wi * 24576;
    for (int seg = t; seg < 3072; seg += 256) {
        int c = seg >> 5, t8 = (seg & 31) << 3;
        *(bf16x8*)(wo + c * 256 + t8) = *(const bf16x8*)(cs + c * WOSTR + t8);
    }
}

// ---------- K4: gather overlapping windows -> x2 (factor pre-applied) ----------
// grid b*96*256 (one block per (b,c,y) row), block 256 (thread = x)
__global__ __launch_bounds__(256) void k_gather(
    const u16* __restrict__ wout, const float* __restrict__ x, float* __restrict__ accb)
{
    int blk = blockIdx.x;
    int y = blk & 255;
    int c = (blk >> 8) % 96;
    int b = blk / (96 * 256);
    int xx = threadIdx.x;

    // y-covering windows (block-uniform)
    int iyl[2]; int ny = 0;
    {
        int c1 = min(17, y / 14), c0 = c1 - 1;
        if (c0 >= 0 && y >= 14 * c0 && y < 14 * c0 + 16) iyl[ny++] = c0;
        if (y >= 14 * c1 && y < 14 * c1 + 16) iyl[ny++] = c1;
        if (y >= 240) iyl[ny++] = 18;
    }
    // x-covering windows (per-thread)
    int ixl[2]; int nx = 0;
    {
        int c1 = min(17, xx / 14), c0 = c1 - 1;
        if (c0 >= 0 && xx >= 14 * c0 && xx < 14 * c0 + 16) ixl[nx++] = c0;
        if (xx >= 14 * c1 && xx < 14 * c1 + 16) ixl[nx++] = c1;
        if (xx >= 240) ixl[nx++] = 18;
    }

    long p = (long)(b * 96 + c) * 65536 + y * 256 + xx;
    float v = (float)(ny * nx) * x[p];
    for (int a = 0; a < ny; ++a) {
        int ty = win_pos(iyl[a]);
        int rowoff = (y - ty) * 16;
        for (int e = 0; e < nx; ++e) {
            int tx = win_pos(ixl[e]);
            int wi = b * 361 + iyl[a] * 19 + ixl[e];
            v += US2F(wout[(long)wi * 24576 + c * 256 + rowoff + (xx - tx)]);
        }
    }
    float f = ((ny == 2) ? 0.5f : 1.f) * ((nx == 2) ? 0.5f : 1.f);
    accb[p] = v * f;
}

// ---------- K5: LN2 + fc1 + GELU (MFMA) ----------
// grid 2048 (64 px/block), block 256 (4 waves); M=64, N=192, K=96
#define XASTR 104
__global__ __launch_bounds__(256) void k_ln2_fc1_mfma(
    const float* __restrict__ accb,
    const float* __restrict__ n2w, const float* __restrict__ n2b,
    const u16* __restrict__ fc1T, const float* __restrict__ fc1b,
    u16* __restrict__ y1)
{
    __shared__ float xs[64 * 97];
    __shared__ __align__(16) u16 xa[64 * XASTR];
    __shared__ float mu_s[64], rs_s[64];
    int p0 = blockIdx.x * 64;
    int b = p0 >> 16, pp = p0 & 65535;
    int tid = threadIdx.x;

    for (int idx = tid; idx < 64 * 96; idx += 256) {
        int c = idx >> 6, px = idx & 63;
        xs[px * 97 + c] = accb[(long)(b * 96 + c) * 65536 + pp + px];
    }
    __syncthreads();
    if (tid < 64) {
        float s = 0.f, ss = 0.f;
        for (int c = 0; c < 96; ++c) { float v = xs[tid * 97 + c]; s += v; ss += v * v; }
        float mu = s * (1.f / 96.f);
        float var = ss * (1.f / 96.f) - mu * mu;
        mu_s[tid] = mu; rs_s[tid] = rsqrtf(var + 1e-5f);
    }
    __syncthreads();
    for (int idx = tid; idx < 64 * 96; idx += 256) {
        int c = idx >> 6, px = idx & 63;
        xa[px * XASTR + c] = F2US((xs[px * 97 + c] - mu_s[px]) * rs_s[px] * n2w[c] + n2b[c]);
    }
    __syncthreads();

    int wvid = tid >> 6, lane = tid & 63, l15 = lane & 15, kg = lane >> 4;
    const f32x4 zc = {0.f, 0.f, 0.f, 0.f};
    bf16x8 a0 = *(const bf16x8*)(xa + (wvid * 16 + l15) * XASTR + 0  + kg * 8);
    bf16x8 a1 = *(const bf16x8*)(xa + (wvid * 16 + l15) * XASTR + 32 + kg * 8);
    bf16x8 a2 = *(const bf16x8*)(xa + (wvid * 16 + l15) * XASTR + 64 + kg * 8);

    for (int nt = 0; nt < 12; ++nt) {
        const u16* wp = fc1T + (nt * 16 + l15) * 96 + kg * 8;
        f32x4 acc = __builtin_amdgcn_mfma_f32_16x16x32_bf16(a0, *(const bf16x8*)(wp), zc, 0, 0, 0);
        acc = __builtin_amdgcn_mfma_f32_16x16x32_bf16(a1, *(const bf16x8*)(wp + 32), acc, 0, 0, 0);
        acc = __builtin_amdgcn_mfma_f32_16x16x32_bf16(a2, *(const bf16x8*)(wp + 64), acc, 0, 0, 0);
        int m = nt * 16 + l15;
        float bb = fc1b[m];
        ushort4 pk;
        pk.x = F2US(gelu_fast(acc[0] + bb));
        pk.y = F2US(gelu_fast(acc[1] + bb));
        pk.z = F2US(gelu_fast(acc[2] + bb));
        pk.w = F2US(gelu_fast(acc[3] + bb));
        *(ushort4*)(y1 + (long)(b * 192 + m) * 65536 + pp + wvid * 16 + kg * 4) = pk;
    }
}

// ---------- K6: depthwise 5x5 conv + GELU + add -> y2 ----------
// grid b*192*4*16 = 24576 (one block per channel-plane 64x16 tile), block 256
__global__ __launch_bounds__(256) void k_dwconv(
    const u16* __restrict__ y1, const float* __restrict__ dww, const float* __restrict__ dwb,
    u16* __restrict__ y2)
{
    __shared__ float tile[20 * 68];
    int blk = blockIdx.x;
    int txt = blk & 3;            // x-tile 0..3
    int tyt = (blk >> 2) & 15;    // y-tile 0..15
    int m   = (blk >> 6) % 192;
    int b   = blk / (64 * 192);
    int bx = txt * 64, by = tyt * 16;
    int tid = threadIdx.x;

    const u16* plane = y1 + (long)(b * 192 + m) * 65536;
    for (int idx = tid; idx < 20 * 68; idx += 256) {
        int ly = idx / 68, lx = idx - ly * 68;
        int sy = by + ly - 2, sx = bx + lx - 2;
        float v = 0.f;
        if (sy >= 0 && sy < 256 && sx >= 0 && sx < 256) v = US2F(plane[sy * 256 + sx]);
        tile[idx] = v;
    }
    // block-uniform weights -> scalar regs
    float w[25];
    #pragma unroll
    for (int j = 0; j < 25; ++j) w[j] = dww[m * 25 + j];
    float bias = dwb[m];
    __syncthreads();

    int tx = tid & 63, ty0 = tid >> 6;
    u16* oplane = y2 + (long)(b * 192 + m) * 65536;
    #pragma unroll
    for (int i = 0; i < 4; ++i) {
        int ty = ty0 * 4 + i;
        float acc = 0.f;
        #pragma unroll
        for (int ky = 0; ky < 5; ++ky)
            #pragma unroll
            for (int kx = 0; kx < 5; ++kx)
                acc += tile[(ty + ky) * 68 + tx + kx] * w[ky * 5 + kx];
        float center = tile[(ty + 2) * 68 + tx + 2];
        float v = center + gelu_fast(acc + bias);
        oplane[(by + ty) * 256 + bx + tx] = F2US(v);
    }
}

// ---------- K7: fc2 + bias + residual (MFMA) ----------
// grid 2048 (64 px/block), block 256 (4 waves); M=64, N=96, K=192
#define Y2STR 200
__global__ __launch_bounds__(256) void k_fc2_mfma(
    const u16* __restrict__ y2, const u16* __restrict__ fc2T, const float* __restrict__ fc2b,
    const float* __restrict__ accb, float* __restrict__ out)
{
    __shared__ __align__(16) u16 ys2[64 * Y2STR];
    int p0 = blockIdx.x * 64;
    int b = p0 >> 16, pp = p0 & 65535;
    int tid = threadIdx.x;
    for (int idx = tid; idx < 64 * 192; idx += 256) {
        int m = idx >> 6, px = idx & 63;
        ys2[px * Y2STR + m] = y2[(long)(b * 192 + m) * 65536 + pp + px];
    }
    __syncthreads();

    int wvid = tid >> 6, lane = tid & 63, l15 = lane & 15, kg = lane >> 4;
    const f32x4 zc = {0.f, 0.f, 0.f, 0.f};
    bf16x8 af[6];
    #pragma unroll
    for (int ks = 0; ks < 6; ++ks)
        af[ks] = *(const bf16x8*)(ys2 + (wvid * 16 + l15) * Y2STR + ks * 32 + kg * 8);

    int pxb = pp + wvid * 16 + kg * 4;

    for (int nt = 0; nt < 6; ++nt) {
        const u16* wp = fc2T + (nt * 16 + l15) * 192 + kg * 8;
        f32x4 acc = zc;
        #pragma unroll
        for (int ks = 0; ks < 6; ++ks)
            acc = __builtin_amdgcn_mfma_f32_16x16x32_bf16(af[ks], *(const bf16x8*)(wp + ks * 32), acc, 0, 0, 0);
        int c = nt * 16 + l15;
        long gbase = (long)(b * 96 + c) * 65536 + pxb;
        float4 av = *(const float4*)(accb + gbase);
        float4 res;
        float bb = fc2b[c];
        res.x = acc[0] + bb + av.x;
        res.y = acc[1] + bb + av.y;
        res.z = acc[2] + bb + av.z;
        res.w = acc[3] + bb + av.w;
        *(float4*)(out + gbase) = res;
    }
}

extern "C" void kernel_launch(void* const* d_in, const int* in_sizes, int n_in,
                              void* d_out, int out_size, void* d_ws, size_t ws_size,
                              hipStream_t stream)
{
    const float* x     = (const float*)d_in[0];
    const float* n1w   = (const float*)d_in[1];
    const float* n1b   = (const float*)d_in[2];
    const float* wq    = (const float*)d_in[3];
    const float* wk    = (const float*)d_in[4];
    const float* wv    = (const float*)d_in[5];
    const float* wproj = (const float*)d_in[6];
    const float* n2w   = (const float*)d_in[7];
    const float* n2b   = (const float*)d_in[8];
    const float* fc1w  = (const float*)d_in[9];
    const float* fc1b  = (const float*)d_in[10];
    const float* dww   = (const float*)d_in[11];
    const float* dwb   = (const float*)d_in[12];
    const float* fc2w  = (const float*)d_in[13];
    const float* fc2b  = (const float*)d_in[14];

    char* ws = (char*)d_ws;
    // memory map (peak 168,759,296 B):
    //   accb fp32 [0, 50.3M)          k_gather -> ln2_fc1, fc2
    //   qkv  bf16 [50.3M, 133.1M)     k_ln_qkv -> k_attn        (dead after attn)
    //   attn bf16 [133.1M, 168.6M)    k_attn -> k_proj          (dead after proj)
    //   wout bf16 [50.3M, 85.8M)     k_proj -> k_gather        (reuses dead qkv head; dead after gather)
    //   y1   bf16 [100.7M, 151.0M)    ln2_fc1 -> dwconv         (dead qkv tail + dead attn head)
    //   y2   bf16 [50.3M, 100.7M)    dwconv -> fc2             (dead wout + dead qkv; below y1)
    //   wT   bf16 [168.6M, +135168)   k_prep -> all GEMMs
    float* accb = (float*)ws;
    u16* qkv  = (u16*)(ws + 50331648);
    u16* attn = (u16*)(ws + 133136384);
    u16* wout = (u16*)(ws + 50331648);
    u16* y1   = (u16*)(ws + 100663296);
    u16* y2   = (u16*)(ws + 50331648);
    u16* wT   = (u16*)(ws + 168624128);
    u16* wqkvT  = wT;
    u16* wprojT = wT + 21504;
    u16* fc1T   = wT + 30720;
    u16* fc2T   = wT + 49152;
    float* out = (float*)d_out;

    k_prep<<<264, 256, 0, stream>>>(wq, wk, wv, wproj, fc1w, fc2w, wT);
    k_ln_qkv_mfma<<<1444, 128, 0, stream>>>(x, n1w, n1b, wqkvT, qkv);
    k_attn_mfma<<<2912, 128, 0, stream>>>(qkv, attn);
    k_proj_mfma<<<722, 256, 0, stream>>>(attn, wprojT, wout);
    k_gather<<<49152, 256, 0, stream>>>(wout, x, accb);
    k_ln2_fc1_mfma<<<2048, 256, 0, stream>>>(accb, n2w, n2b, fc1T, fc1b, y1);
    k_dwconv<<<24576, 256, 0, stream>>>(y1, dww, dwb, y2);
    k_fc2_mfma<<<2048, 256, 0, stream>>>(y2, fc2T, fc2b, accb, out);
}